// Round 20
// baseline (180.576 us; speedup 1.0000x reference)
//
#include <hip/hip_runtime.h>

#define ND 256       // embedding dim
#define NK 512       // centroids
#define LM2 0.0625f  // lambda^2
#define DELTA 0.25f  // approx top-2 gap below this -> exact fp32 rescore

typedef _Float16 f16x8 __attribute__((ext_vector_type(8)));
typedef float f32x4 __attribute__((ext_vector_type(4)));
typedef unsigned short u16x8 __attribute__((ext_vector_type(8)));
typedef unsigned short u16x4 __attribute__((ext_vector_type(4)));

// async 16B global->LDS (zero VGPR staging). LDS dest is wave-uniform base
// (HW adds lane*16); global src is per-lane.
#define GLD16(GSRC, LDST)                                                      \
    __builtin_amdgcn_global_load_lds(                                         \
        (const __attribute__((address_space(1))) void*)(GSRC),                \
        (__attribute__((address_space(3))) void*)(LDST), 16, 0, 0)

// ---------------- prep: csq[k] + fp16 centroids, 4 panels of 128 cols --------
// Cf layout: [panel 4][krow 32][col 128][8], krow = (d>>5)*4 + ((d>>3)&3).
// Same 16B frag granule as r13-r19 (verified 0 conflicts); panel width doubled.
__global__ __launch_bounds__(64) void prep_kernel(const float* __restrict__ Cg,
                                                  float* __restrict__ csq,
                                                  unsigned short* __restrict__ Cf) {
    const int k = blockIdx.x, lane = threadIdx.x;
    float4 v = *(const float4*)(Cg + (size_t)k * ND + lane * 4);
    float s = v.x * v.x + v.y * v.y + v.z * v.z + v.w * v.w;
#pragma unroll
    for (int m = 1; m <= 32; m <<= 1) s += __shfl_xor(s, m, 64);
    if (lane == 0) csq[k] = s;
    u16x4 h;
    h[0] = __builtin_bit_cast(unsigned short, (_Float16)v.x);
    h[1] = __builtin_bit_cast(unsigned short, (_Float16)v.y);
    h[2] = __builtin_bit_cast(unsigned short, (_Float16)v.z);
    h[3] = __builtin_bit_cast(unsigned short, (_Float16)v.w);
    const int panel = k >> 7, col = k & 127;
    const int krow = (lane >> 3) * 4 + ((lane >> 1) & 3);  // d0 = lane*4
    const size_t idx = ((size_t)panel << 15) + ((((size_t)krow << 7) + col) << 3) + ((lane & 1) << 2);
    *(u16x4*)(Cf + idx) = h;
}

// ---------------- main: r19 swapped-MFMA structure, HALF the phase count -----
// grid 256 x 1024 thr: 512 rows/block (16 waves x 32), ONE generation, 1 bl/CU.
// 4 panels of 128 cols (64 KB each, dbuf = 128 KB LDS) -> 4 barriers instead
// of 8; per-phase compute doubles while per-lane liveness is UNCHANGED from
// r19's no-spill ~100 regs (Ef[2][8]=64 + acc 8 + keys 4). Each centroid
// A-frag ds_read feeds both E row-groups (2x reuse, r19-proven). Spill
// tripwire: WRITE_SIZE.
__global__ __launch_bounds__(1024, 1) void kmeans_mfma(
    const float* __restrict__ E, const unsigned short* __restrict__ Cf,
    const float* __restrict__ csq, uint2* __restrict__ partials,
    float* __restrict__ e2s) {
    __shared__ unsigned short Bbuf[2][32768];  // 2 x 64 KB

    const int tid = threadIdx.x;
    const int lane = tid & 63, wid = tid >> 6;  // wid 0..15
    const int l15 = lane & 15, l4 = lane >> 4;
    const int rowbase = blockIdx.x << 9;  // 512 rows/block
    const int wrow = rowbase + wid * 32;  // 32 rows/wave

    // ---- issue panel 0 staging (flies during E-load); 4 slots per wave ----
#pragma unroll
    for (int i = 0; i < 4; ++i)
        GLD16(Cf + (((size_t)(wid * 4 + i) * 64 + lane) << 3),
              &Bbuf[0][(size_t)(wid * 4 + i) << 9]);

    // ---- E load: rows wrow+g*16+l15 (g=0,1), chunks of 4 ks (r13-proven) ----
    f16x8 Ef[2][8];  // [g][ks], 64 VGPR; B-frag: col=l15(row), k=l4*8 (verified)
    float e2 = 0.f;
#pragma unroll
    for (int g = 0; g < 2; ++g) {
        const float* ap = E + (size_t)(wrow + g * 16 + l15) * ND + l4 * 8;
#pragma unroll
        for (int half = 0; half < 2; ++half) {
            float4 t[8];
#pragma unroll
            for (int q = 0; q < 4; ++q) {
                t[q * 2]     = *(const float4*)(ap + (half * 4 + q) * 32);
                t[q * 2 + 1] = *(const float4*)(ap + (half * 4 + q) * 32 + 4);
            }
#pragma unroll
            for (int q = 0; q < 4; ++q) {
                float4 v0 = t[q * 2], v1 = t[q * 2 + 1];
                e2 += v0.x * v0.x + v0.y * v0.y + v0.z * v0.z + v0.w * v0.w +
                      v1.x * v1.x + v1.y * v1.y + v1.z * v1.z + v1.w * v1.w;
                u16x8 h;
                h[0] = __builtin_bit_cast(unsigned short, (_Float16)v0.x);
                h[1] = __builtin_bit_cast(unsigned short, (_Float16)v0.y);
                h[2] = __builtin_bit_cast(unsigned short, (_Float16)v0.z);
                h[3] = __builtin_bit_cast(unsigned short, (_Float16)v0.w);
                h[4] = __builtin_bit_cast(unsigned short, (_Float16)v1.x);
                h[5] = __builtin_bit_cast(unsigned short, (_Float16)v1.y);
                h[6] = __builtin_bit_cast(unsigned short, (_Float16)v1.z);
                h[7] = __builtin_bit_cast(unsigned short, (_Float16)v1.w);
                Ef[g][half * 4 + q] = __builtin_bit_cast(f16x8, h);
            }
        }
    }

    unsigned k1[2] = {0u, 0u}, k2[2] = {0u, 0u};  // per row-group top-2 keys

#pragma unroll 1
    for (int p = 0; p < 4; ++p) {
        __syncthreads();  // drains own vmcnt: panel p staged; buf[(p+1)&1] free
        if (p < 3) {      // issue next panel (lands during this panel's compute)
            const unsigned short* gsrc = Cf + ((size_t)(p + 1) << 15);
            unsigned short* ldst = (unsigned short*)Bbuf[(p + 1) & 1];
#pragma unroll
            for (int i = 0; i < 4; ++i)
                GLD16(gsrc + (((size_t)(wid * 4 + i) * 64 + lane) << 3),
                      &ldst[(size_t)(wid * 4 + i) << 9]);
        }
        const unsigned short* cur = Bbuf[p & 1];
        // 8 centroid 16-tiles per panel; each A-frag read feeds BOTH row-groups
#pragma unroll
        for (int n = 0; n < 8; ++n) {
            const float4 csp = *(const float4*)(csq + (p << 7) + n * 16 + l4 * 4);
            f32x4 a0 = {}, a1 = {};
#pragma unroll
            for (int ks = 0; ks < 8; ++ks) {
                const u16x8 bfr =
                    *(const u16x8*)&cur[(size_t)((((ks << 2) + l4) << 7) + n * 16 + l15) << 3];
                const f16x8 cf = __builtin_bit_cast(f16x8, bfr);  // A-frag: 16 centroids x 32k
                a0 = __builtin_amdgcn_mfma_f32_16x16x32_f16(cf, Ef[0][ks], a0, 0, 0, 0);
                a1 = __builtin_amdgcn_mfma_f32_16x16x32_f16(cf, Ef[1][ks], a1, 0, 0, 0);
            }
            // fold: lane holds centroids c = p*128+n*16+l4*4+j for row (l15, g)
            const unsigned kbase = (unsigned)(NK - 1 - ((p << 7) + n * 16 + l4 * 4));
            const float cs[4] = {csp.x, csp.y, csp.z, csp.w};
#pragma unroll
            for (int g = 0; g < 2; ++g) {
                const f32x4 ag = g ? a1 : a0;
#pragma unroll
                for (int j = 0; j < 4; ++j) {
                    const float s = fmaf(-2.f, ag[j], cs[j]);
                    const unsigned b = __builtin_bit_cast(unsigned, s);
                    const unsigned mono = b ^ ((unsigned)((int)b >> 31) | 0x80000000u);
                    const unsigned key = (mono & 0xFFFFFE00u) | (kbase - (unsigned)j);
                    const unsigned mn = min(k1[g], key);
                    k1[g] = max(k1[g], key);
                    k2[g] = max(k2[g], mn);
                }
            }
        }
    }

    // ---- merge across the 4 l4-lane-groups (rows are per-(l15,g)) ----
#pragma unroll
    for (int g = 0; g < 2; ++g) {
        unsigned a = k1[g], b2 = k2[g];
#pragma unroll
        for (int mk = 16; mk <= 32; mk <<= 1) {
            const unsigned oa = __shfl_xor(a, mk, 64);
            const unsigned ob = __shfl_xor(b2, mk, 64);
            const unsigned mn = min(a, oa);
            a = max(a, oa);
            b2 = max(max(b2, ob), mn);
        }
        if (l4 == 0) {
            uint2 o;
            o.x = a;
            o.y = b2;
            partials[wrow + g * 16 + l15] = o;  // FINAL top-2 for this row
        }
    }

    // ---- e2 partial (each element counted exactly once chip-wide) ----
#pragma unroll
    for (int mk = 1; mk <= 32; mk <<= 1) e2 += __shfl_xor(e2, mk, 64);
    if (lane == 0) e2s[blockIdx.x * 16 + wid] = e2;
}

// ---------------- combine: decode final top-2, rescore near-ties -------------
__global__ __launch_bounds__(256) void combine_kernel(
    const uint2* __restrict__ partials, const float* __restrict__ csq,
    const float* __restrict__ E, const float* __restrict__ Cg,
    float* __restrict__ out, float* __restrict__ sum2) {
    const int n = blockIdx.x * 256 + threadIdx.x;
    const uint2 kk = partials[n];
    const unsigned m1 = kk.x & 0xFFFFFE00u;
    float v1 = __builtin_bit_cast(float, (m1 & 0x80000000u) ? (m1 ^ 0x80000000u) : ~m1);
    int i1 = (int)(NK - 1) - (int)(kk.x & 511u);
    const unsigned m2 = kk.y & 0xFFFFFE00u;
    const float v2 = __builtin_bit_cast(float, (m2 & 0x80000000u) ? (m2 ^ 0x80000000u) : ~m2);
    const int i2 = (int)(NK - 1) - (int)(kk.y & 511u);

    if (v1 - v2 <= DELTA) {  // near-tie: exact fp32 rescore of both candidates
        const float* e = E + (size_t)n * ND;
        const float* c1p = Cg + (size_t)i1 * ND;
        const float* c2p = Cg + (size_t)i2 * ND;
        float d1 = 0.f, d2 = 0.f;
        for (int d = 0; d < ND; d += 4) {
            float4 ev = *(const float4*)(e + d);
            float4 cv1 = *(const float4*)(c1p + d);
            float4 cv2 = *(const float4*)(c2p + d);
            d1 += ev.x * cv1.x + ev.y * cv1.y + ev.z * cv1.z + ev.w * cv1.w;
            d2 += ev.x * cv2.x + ev.y * cv2.y + ev.z * cv2.z + ev.w * cv2.w;
        }
        const float s1 = csq[i1] - 2.f * d1;
        const float s2 = csq[i2] - 2.f * d2;
        if (s2 > s1 || (s2 == s1 && i2 < i1)) { v1 = s2; i1 = i2; } else { v1 = s1; }
    }
    out[1 + n] = (float)i1;
    float s = v1;
#pragma unroll
    for (int mk = 1; mk <= 32; mk <<= 1) s += __shfl_xor(s, mk, 64);
    __shared__ float wsm[4];
    const int lane = threadIdx.x & 63, wd = threadIdx.x >> 6;
    if (lane == 0) wsm[wd] = s;
    __syncthreads();
    if (threadIdx.x == 0) sum2[blockIdx.x] = wsm[0] + wsm[1] + wsm[2] + wsm[3];
}

// ---------------- final: loss = lambda^2 * (sum e^2 + sum row maxima) --------
__global__ __launch_bounds__(256) void final_kernel(const float* __restrict__ e2s,
                                                    const float* __restrict__ sum2,
                                                    float* __restrict__ out) {
    float s = 0.f;
    for (int i = threadIdx.x; i < 4096; i += 256) s += e2s[i];
    for (int i = threadIdx.x; i < 512; i += 256) s += sum2[i];
#pragma unroll
    for (int mk = 1; mk <= 32; mk <<= 1) s += __shfl_xor(s, mk, 64);
    __shared__ float wsm[4];
    const int lane = threadIdx.x & 63, wd = threadIdx.x >> 6;
    if (lane == 0) wsm[wd] = s;
    __syncthreads();
    if (threadIdx.x == 0) out[0] = LM2 * (wsm[0] + wsm[1] + wsm[2] + wsm[3]);
}

extern "C" void kernel_launch(void* const* d_in, const int* in_sizes, int n_in,
                              void* d_out, int out_size, void* d_ws, size_t ws_size,
                              hipStream_t stream) {
    (void)n_in; (void)out_size; (void)ws_size;
    const float* E = (const float*)d_in[0];
    const float* Cg = (const float*)d_in[1];
    float* out = (float*)d_out;

    // ws (floats): csq[512] | e2s[4096] | sum2[512] | Cf16 (256KB) | partials (1MB)
    float* wsf = (float*)d_ws;
    float* csq = wsf;
    float* e2s = wsf + 512;
    float* sum2 = wsf + 4608;
    unsigned short* Cf = (unsigned short*)(wsf + 5120);
    uint2* partials = (uint2*)(wsf + 5120 + 65536);

    const int N = in_sizes[0] / ND;  // 131072
    const int nblk = N >> 9;         // 256 blocks of 512 rows (one generation)

    prep_kernel<<<NK, 64, 0, stream>>>(Cg, csq, Cf);
    kmeans_mfma<<<nblk, 1024, 0, stream>>>(E, Cf, csq, partials, e2s);
    combine_kernel<<<N / 256, 256, 0, stream>>>(partials, csq, E, Cg, out, sum2);
    final_kernel<<<1, 256, 0, stream>>>(e2s, sum2, out);
}

// Round 21
// 143.660 us; speedup vs baseline: 1.2570x; 1.2570x over previous
//
#include <hip/hip_runtime.h>

#define ND 256       // embedding dim
#define NK 512       // centroids
#define LM2 0.0625f  // lambda^2
#define DELTA 0.25f  // approx top-2 gap below this -> exact fp32 rescore

typedef _Float16 f16x8 __attribute__((ext_vector_type(8)));
typedef float f32x4 __attribute__((ext_vector_type(4)));
typedef unsigned short u16x8 __attribute__((ext_vector_type(8)));
typedef unsigned short u16x4 __attribute__((ext_vector_type(4)));

// ---------------- prep: csq[k] + fp16 centroids in A-frag granule order ------
// Cf layout: [krow 32][col 512][8], krow = (d>>5)*4 + ((d>>3)&3).
// A 16B granule = one lane's MFMA A-operand slice (16 centroids x 32 k per
// tile) — the SAME bytes r19 staged through LDS, now read directly from L2
// (Cf = 256 KB, L2-resident).
__global__ __launch_bounds__(64) void prep_kernel(const float* __restrict__ Cg,
                                                  float* __restrict__ csq,
                                                  unsigned short* __restrict__ Cf) {
    const int k = blockIdx.x, lane = threadIdx.x;
    float4 v = *(const float4*)(Cg + (size_t)k * ND + lane * 4);
    float s = v.x * v.x + v.y * v.y + v.z * v.z + v.w * v.w;
#pragma unroll
    for (int m = 1; m <= 32; m <<= 1) s += __shfl_xor(s, m, 64);
    if (lane == 0) csq[k] = s;
    u16x4 h;
    h[0] = __builtin_bit_cast(unsigned short, (_Float16)v.x);
    h[1] = __builtin_bit_cast(unsigned short, (_Float16)v.y);
    h[2] = __builtin_bit_cast(unsigned short, (_Float16)v.z);
    h[3] = __builtin_bit_cast(unsigned short, (_Float16)v.w);
    const int krow = (lane >> 3) * 4 + ((lane >> 1) & 3);  // d0 = lane*4
    const size_t idx = (((size_t)krow * NK + k) << 3) + ((lane & 1) << 2);
    *(u16x4*)(Cf + idx) = h;
}

// ---------------- main: ZERO barriers, ZERO LDS — pure streaming MFMA --------
// grid 1024 x 256 thr (4 waves x 32 rows = 128 rows/block), (256,2) = the
// allocator-safe envelope (VGPR liveness ~118 < 128: Ef 64 + cf 32 + acc 8 +
// keys 4 + addr). D[centroid][row] = mfma(A=cf from L2, B=Ef in regs):
// every wave runs fully independently — no __syncthreads in the kernel.
// Per tile: 8 independent 16B L2 loads + 16 MFMA; the ~200cyc L2 latency is
// hidden by 4 waves/SIMD TLP and the previous tile's fold. Chip L2 traffic
// 512 MB (~16 us at L2 BW). Spill tripwire: WRITE_SIZE.
__global__ __launch_bounds__(256, 2) void kmeans_mfma(
    const float* __restrict__ E, const unsigned short* __restrict__ Cf,
    const float* __restrict__ csq, uint2* __restrict__ partials,
    float* __restrict__ e2s) {
    const int tid = threadIdx.x;
    const int lane = tid & 63, wid = tid >> 6;  // wid 0..3
    const int l15 = lane & 15, l4 = lane >> 4;
    const int wrow = (blockIdx.x << 7) + wid * 32;  // 32 rows/wave

    // ---- E load: rows wrow+g*16+l15 (g=0,1), chunks of 4 ks (r13-proven) ----
    f16x8 Ef[2][8];  // [g][ks], 64 VGPR; B-frag: col=l15(row), k=l4*8 (verified)
    float e2 = 0.f;
#pragma unroll
    for (int g = 0; g < 2; ++g) {
        const float* ap = E + (size_t)(wrow + g * 16 + l15) * ND + l4 * 8;
#pragma unroll
        for (int half = 0; half < 2; ++half) {
            float4 t[8];
#pragma unroll
            for (int q = 0; q < 4; ++q) {
                t[q * 2]     = *(const float4*)(ap + (half * 4 + q) * 32);
                t[q * 2 + 1] = *(const float4*)(ap + (half * 4 + q) * 32 + 4);
            }
#pragma unroll
            for (int q = 0; q < 4; ++q) {
                float4 v0 = t[q * 2], v1 = t[q * 2 + 1];
                e2 += v0.x * v0.x + v0.y * v0.y + v0.z * v0.z + v0.w * v0.w +
                      v1.x * v1.x + v1.y * v1.y + v1.z * v1.z + v1.w * v1.w;
                u16x8 h;
                h[0] = __builtin_bit_cast(unsigned short, (_Float16)v0.x);
                h[1] = __builtin_bit_cast(unsigned short, (_Float16)v0.y);
                h[2] = __builtin_bit_cast(unsigned short, (_Float16)v0.z);
                h[3] = __builtin_bit_cast(unsigned short, (_Float16)v0.w);
                h[4] = __builtin_bit_cast(unsigned short, (_Float16)v1.x);
                h[5] = __builtin_bit_cast(unsigned short, (_Float16)v1.y);
                h[6] = __builtin_bit_cast(unsigned short, (_Float16)v1.z);
                h[7] = __builtin_bit_cast(unsigned short, (_Float16)v1.w);
                Ef[g][half * 4 + q] = __builtin_bit_cast(f16x8, h);
            }
        }
    }

    // per-lane A-frag base: granule (krow = ks*4 + l4, col = n*16 + l15)
    const unsigned short* Cfl = Cf + (((size_t)l4 * NK + l15) << 3);

    unsigned k1[2] = {0u, 0u}, k2[2] = {0u, 0u};  // per row-group top-2 keys

#pragma unroll 1
    for (int n = 0; n < 32; ++n) {
        const float4 csp = *(const float4*)(csq + n * 16 + l4 * 4);
        // 8 independent 16B loads from L2 (one per ks), then 16 MFMA
        u16x8 cf[8];
#pragma unroll
        for (int ks = 0; ks < 8; ++ks)
            cf[ks] = *(const u16x8*)(Cfl + ((((size_t)ks * 4) * NK + (size_t)n * 16) << 3));
        f32x4 a0 = {}, a1 = {};
#pragma unroll
        for (int ks = 0; ks < 8; ++ks) {
            const f16x8 c = __builtin_bit_cast(f16x8, cf[ks]);
            a0 = __builtin_amdgcn_mfma_f32_16x16x32_f16(c, Ef[0][ks], a0, 0, 0, 0);
            a1 = __builtin_amdgcn_mfma_f32_16x16x32_f16(c, Ef[1][ks], a1, 0, 0, 0);
        }
        // fold: lane holds centroids c = n*16+l4*4+j for row (l15, g)
        const unsigned kbase = (unsigned)(NK - 1 - (n * 16 + l4 * 4));
        const float cs[4] = {csp.x, csp.y, csp.z, csp.w};
#pragma unroll
        for (int g = 0; g < 2; ++g) {
            const f32x4 ag = g ? a1 : a0;
#pragma unroll
            for (int j = 0; j < 4; ++j) {
                const float s = fmaf(-2.f, ag[j], cs[j]);
                const unsigned b = __builtin_bit_cast(unsigned, s);
                const unsigned mono = b ^ ((unsigned)((int)b >> 31) | 0x80000000u);
                const unsigned key = (mono & 0xFFFFFE00u) | (kbase - (unsigned)j);
                const unsigned mn = min(k1[g], key);
                k1[g] = max(k1[g], key);
                k2[g] = max(k2[g], mn);
            }
        }
    }

    // ---- merge across the 4 l4-lane-groups (rows are per-(l15,g)) ----
#pragma unroll
    for (int g = 0; g < 2; ++g) {
        unsigned a = k1[g], b2 = k2[g];
#pragma unroll
        for (int mk = 16; mk <= 32; mk <<= 1) {
            const unsigned oa = __shfl_xor(a, mk, 64);
            const unsigned ob = __shfl_xor(b2, mk, 64);
            const unsigned mn = min(a, oa);
            a = max(a, oa);
            b2 = max(max(b2, ob), mn);
        }
        if (l4 == 0) {
            uint2 o;
            o.x = a;
            o.y = b2;
            partials[wrow + g * 16 + l15] = o;  // FINAL top-2 for this row
        }
    }

    // ---- e2 partial (each element counted exactly once chip-wide) ----
#pragma unroll
    for (int mk = 1; mk <= 32; mk <<= 1) e2 += __shfl_xor(e2, mk, 64);
    if (lane == 0) e2s[blockIdx.x * 4 + wid] = e2;
}

// ---------------- combine: decode final top-2, rescore near-ties -------------
__global__ __launch_bounds__(256) void combine_kernel(
    const uint2* __restrict__ partials, const float* __restrict__ csq,
    const float* __restrict__ E, const float* __restrict__ Cg,
    float* __restrict__ out, float* __restrict__ sum2) {
    const int n = blockIdx.x * 256 + threadIdx.x;
    const uint2 kk = partials[n];
    const unsigned m1 = kk.x & 0xFFFFFE00u;
    float v1 = __builtin_bit_cast(float, (m1 & 0x80000000u) ? (m1 ^ 0x80000000u) : ~m1);
    int i1 = (int)(NK - 1) - (int)(kk.x & 511u);
    const unsigned m2 = kk.y & 0xFFFFFE00u;
    const float v2 = __builtin_bit_cast(float, (m2 & 0x80000000u) ? (m2 ^ 0x80000000u) : ~m2);
    const int i2 = (int)(NK - 1) - (int)(kk.y & 511u);

    if (v1 - v2 <= DELTA) {  // near-tie: exact fp32 rescore of both candidates
        const float* e = E + (size_t)n * ND;
        const float* c1p = Cg + (size_t)i1 * ND;
        const float* c2p = Cg + (size_t)i2 * ND;
        float d1 = 0.f, d2 = 0.f;
        for (int d = 0; d < ND; d += 4) {
            float4 ev = *(const float4*)(e + d);
            float4 cv1 = *(const float4*)(c1p + d);
            float4 cv2 = *(const float4*)(c2p + d);
            d1 += ev.x * cv1.x + ev.y * cv1.y + ev.z * cv1.z + ev.w * cv1.w;
            d2 += ev.x * cv2.x + ev.y * cv2.y + ev.z * cv2.z + ev.w * cv2.w;
        }
        const float s1 = csq[i1] - 2.f * d1;
        const float s2 = csq[i2] - 2.f * d2;
        if (s2 > s1 || (s2 == s1 && i2 < i1)) { v1 = s2; i1 = i2; } else { v1 = s1; }
    }
    out[1 + n] = (float)i1;
    float s = v1;
#pragma unroll
    for (int mk = 1; mk <= 32; mk <<= 1) s += __shfl_xor(s, mk, 64);
    __shared__ float wsm[4];
    const int lane = threadIdx.x & 63, wd = threadIdx.x >> 6;
    if (lane == 0) wsm[wd] = s;
    __syncthreads();
    if (threadIdx.x == 0) sum2[blockIdx.x] = wsm[0] + wsm[1] + wsm[2] + wsm[3];
}

// ---------------- final: loss = lambda^2 * (sum e^2 + sum row maxima) --------
__global__ __launch_bounds__(256) void final_kernel(const float* __restrict__ e2s,
                                                    const float* __restrict__ sum2,
                                                    float* __restrict__ out) {
    float s = 0.f;
    for (int i = threadIdx.x; i < 4096; i += 256) s += e2s[i];
    for (int i = threadIdx.x; i < 512; i += 256) s += sum2[i];
#pragma unroll
    for (int mk = 1; mk <= 32; mk <<= 1) s += __shfl_xor(s, mk, 64);
    __shared__ float wsm[4];
    const int lane = threadIdx.x & 63, wd = threadIdx.x >> 6;
    if (lane == 0) wsm[wd] = s;
    __syncthreads();
    if (threadIdx.x == 0) out[0] = LM2 * (wsm[0] + wsm[1] + wsm[2] + wsm[3]);
}

extern "C" void kernel_launch(void* const* d_in, const int* in_sizes, int n_in,
                              void* d_out, int out_size, void* d_ws, size_t ws_size,
                              hipStream_t stream) {
    (void)n_in; (void)out_size; (void)ws_size;
    const float* E = (const float*)d_in[0];
    const float* Cg = (const float*)d_in[1];
    float* out = (float*)d_out;

    // ws (floats): csq[512] | e2s[4096] | sum2[512] | Cf16 (256KB) | partials (1MB)
    float* wsf = (float*)d_ws;
    float* csq = wsf;
    float* e2s = wsf + 512;
    float* sum2 = wsf + 4608;
    unsigned short* Cf = (unsigned short*)(wsf + 5120);
    uint2* partials = (uint2*)(wsf + 5120 + 65536);

    const int N = in_sizes[0] / ND;  // 131072
    const int nblk = N >> 7;         // 1024 blocks of 128 rows

    prep_kernel<<<NK, 64, 0, stream>>>(Cg, csq, Cf);
    kmeans_mfma<<<nblk, 256, 0, stream>>>(E, Cf, csq, partials, e2s);
    combine_kernel<<<N / 256, 256, 0, stream>>>(partials, csq, E, Cg, out, sum2);
    final_kernel<<<1, 256, 0, stream>>>(e2s, sum2, out);
}

// Round 22
// 108.885 us; speedup vs baseline: 1.6584x; 1.3194x over previous
//
#include <hip/hip_runtime.h>

#define ND 256       // embedding dim
#define NK 512       // centroids
#define LM2 0.0625f  // lambda^2
#define DELTA 0.25f  // approx top-2 gap below this -> exact fp32 rescore

typedef _Float16 f16x8 __attribute__((ext_vector_type(8)));
typedef float f32x4 __attribute__((ext_vector_type(4)));
typedef unsigned short u16x8 __attribute__((ext_vector_type(8)));
typedef unsigned short u16x4 __attribute__((ext_vector_type(4)));

// async 16B global->LDS (zero VGPR staging). LDS dest is wave-uniform base
// (HW adds lane*16); global src is per-lane.
#define GLD16(GSRC, LDST)                                                      \
    __builtin_amdgcn_global_load_lds(                                         \
        (const __attribute__((address_space(1))) void*)(GSRC),                \
        (__attribute__((address_space(3))) void*)(LDST), 16, 0, 0)

// ---------------- prep: csq[k] + fp16 centroids in A-frag granule order ------
// Cf layout: [krow 32][col 512][8], krow = (d>>5)*4 + ((d>>3)&3).
// 16B granule = one lane's MFMA A-operand slice (verified r19/r21).
__global__ __launch_bounds__(64) void prep_kernel(const float* __restrict__ Cg,
                                                  float* __restrict__ csq,
                                                  unsigned short* __restrict__ Cf) {
    const int k = blockIdx.x, lane = threadIdx.x;
    float4 v = *(const float4*)(Cg + (size_t)k * ND + lane * 4);
    float s = v.x * v.x + v.y * v.y + v.z * v.z + v.w * v.w;
#pragma unroll
    for (int m = 1; m <= 32; m <<= 1) s += __shfl_xor(s, m, 64);
    if (lane == 0) csq[k] = s;
    u16x4 h;
    h[0] = __builtin_bit_cast(unsigned short, (_Float16)v.x);
    h[1] = __builtin_bit_cast(unsigned short, (_Float16)v.y);
    h[2] = __builtin_bit_cast(unsigned short, (_Float16)v.z);
    h[3] = __builtin_bit_cast(unsigned short, (_Float16)v.w);
    const int krow = (lane >> 3) * 4 + ((lane >> 1) & 3);  // d0 = lane*4
    const size_t idx = (((size_t)krow * NK + k) << 3) + ((lane & 1) << 2);
    *(u16x4*)(Cf + idx) = h;
}

// ---------------- main: ONE barrier total — half-Cf in LDS, free-running waves
// grid 1024 = 2 col-halves x 512 row-groups (256 rows each); 512 thr (8 waves
// x 32 rows). LDS = 128 KB (one half of Cf, single-buffered) -> 1 block/CU,
// 2 waves/SIMD; __launch_bounds__(512,1) gives the allocator a 256-VGPR budget
// (spill-proof; liveness ~160). After the single __syncthreads, waves run with
// ZERO synchronization: 16 tiles x {8 ds_read_b128 A-frags + 16 MFMA + fold},
// unroll 2 so tile n+1's LDS reads pipeline under tile n's MFMAs.
__global__ __launch_bounds__(512, 1) void kmeans_mfma(
    const float* __restrict__ E, const unsigned short* __restrict__ Cf,
    const float* __restrict__ csq, uint2* __restrict__ partials,
    float* __restrict__ e2s) {
    __shared__ unsigned short Blds[65536];  // 128 KB: half of Cf

    const int tid = threadIdx.x;
    const int lane = tid & 63, wid = tid >> 6;  // wid 0..7
    const int l15 = lane & 15, l4 = lane >> 4;
    const int half = blockIdx.x & 1;            // centroid half: cols half*256..
    const int rowgrp = blockIdx.x >> 1;
    const int wrow = (rowgrp << 8) + wid * 32;  // 32 rows/wave

    // ---- stage this half's 128 KB (granules: krow 0..31 x col 0..255) ----
    // LDS granule gidx = (wid*16+i)*64 + lane; krow = gidx>>8, col = gidx&255.
    // Global short offset = ((krow<<9) + half*256 + col) << 3 (coalesced 1KB/op).
#pragma unroll
    for (int i = 0; i < 16; ++i) {
        const int gblk = wid * 16 + i;           // 64-granule block, same krow
        const int krow = (gblk * 64) >> 8;
        const int col0 = (gblk * 64) & 255;
        GLD16(Cf + ((((size_t)krow << 9) + half * 256 + col0 + lane) << 3),
              &Blds[(size_t)gblk << 9]);
    }

    // ---- E load: rows wrow+g*16+l15 (g=0,1), chunks of 4 ks (r13-proven) ----
    f16x8 Ef[2][8];  // [g][ks], 64 VGPR; B-frag: col=l15(row), k=l4*8 (verified)
    float e2 = 0.f;
#pragma unroll
    for (int g = 0; g < 2; ++g) {
        const float* ap = E + (size_t)(wrow + g * 16 + l15) * ND + l4 * 8;
#pragma unroll
        for (int hf = 0; hf < 2; ++hf) {
            float4 t[8];
#pragma unroll
            for (int q = 0; q < 4; ++q) {
                t[q * 2]     = *(const float4*)(ap + (hf * 4 + q) * 32);
                t[q * 2 + 1] = *(const float4*)(ap + (hf * 4 + q) * 32 + 4);
            }
#pragma unroll
            for (int q = 0; q < 4; ++q) {
                float4 v0 = t[q * 2], v1 = t[q * 2 + 1];
                if (half == 0)
                    e2 += v0.x * v0.x + v0.y * v0.y + v0.z * v0.z + v0.w * v0.w +
                          v1.x * v1.x + v1.y * v1.y + v1.z * v1.z + v1.w * v1.w;
                u16x8 h;
                h[0] = __builtin_bit_cast(unsigned short, (_Float16)v0.x);
                h[1] = __builtin_bit_cast(unsigned short, (_Float16)v0.y);
                h[2] = __builtin_bit_cast(unsigned short, (_Float16)v0.z);
                h[3] = __builtin_bit_cast(unsigned short, (_Float16)v0.w);
                h[4] = __builtin_bit_cast(unsigned short, (_Float16)v1.x);
                h[5] = __builtin_bit_cast(unsigned short, (_Float16)v1.y);
                h[6] = __builtin_bit_cast(unsigned short, (_Float16)v1.z);
                h[7] = __builtin_bit_cast(unsigned short, (_Float16)v1.w);
                Ef[g][hf * 4 + q] = __builtin_bit_cast(f16x8, h);
            }
        }
    }

    __syncthreads();  // THE ONLY BARRIER: half-panel staged (drains gload vmcnt)

    unsigned k1[2] = {0u, 0u}, k2[2] = {0u, 0u};  // per row-group top-2 keys
    const int colbase = half * 256;

#pragma unroll 2
    for (int n = 0; n < 16; ++n) {
        const float4 csp = *(const float4*)(csq + colbase + n * 16 + l4 * 4);
        // 8 A-frag ds_read_b128 (granule krow=ks*4+l4, col=n*16+l15)
        u16x8 cf[8];
#pragma unroll
        for (int ks = 0; ks < 8; ++ks)
            cf[ks] = *(const u16x8*)&Blds[(size_t)(((ks * 4 + l4) << 8) + n * 16 + l15) << 3];
        f32x4 a0 = {}, a1 = {};
#pragma unroll
        for (int ks = 0; ks < 8; ++ks) {
            const f16x8 c = __builtin_bit_cast(f16x8, cf[ks]);
            a0 = __builtin_amdgcn_mfma_f32_16x16x32_f16(c, Ef[0][ks], a0, 0, 0, 0);
            a1 = __builtin_amdgcn_mfma_f32_16x16x32_f16(c, Ef[1][ks], a1, 0, 0, 0);
        }
        // fold: lane holds centroids c = colbase+n*16+l4*4+j for row (l15, g)
        const unsigned kbase = (unsigned)(NK - 1 - (colbase + n * 16 + l4 * 4));
        const float cs[4] = {csp.x, csp.y, csp.z, csp.w};
#pragma unroll
        for (int g = 0; g < 2; ++g) {
            const f32x4 ag = g ? a1 : a0;
#pragma unroll
            for (int j = 0; j < 4; ++j) {
                const float s = fmaf(-2.f, ag[j], cs[j]);
                const unsigned b = __builtin_bit_cast(unsigned, s);
                const unsigned mono = b ^ ((unsigned)((int)b >> 31) | 0x80000000u);
                const unsigned key = (mono & 0xFFFFFE00u) | (kbase - (unsigned)j);
                const unsigned mn = min(k1[g], key);
                k1[g] = max(k1[g], key);
                k2[g] = max(k2[g], mn);
            }
        }
    }

    // ---- merge across the 4 l4-lane-groups; write this half's top-2 ----
#pragma unroll
    for (int g = 0; g < 2; ++g) {
        unsigned a = k1[g], b2 = k2[g];
#pragma unroll
        for (int mk = 16; mk <= 32; mk <<= 1) {
            const unsigned oa = __shfl_xor(a, mk, 64);
            const unsigned ob = __shfl_xor(b2, mk, 64);
            const unsigned mn = min(a, oa);
            a = max(a, oa);
            b2 = max(max(b2, ob), mn);
        }
        if (l4 == 0) {
            uint2 o;
            o.x = a;
            o.y = b2;
            partials[(size_t)((wrow + g * 16 + l15) << 1) + half] = o;
        }
    }

    // ---- e2 partial (half==0 only: each element counted once chip-wide) ----
    if (half == 0) {
#pragma unroll
        for (int mk = 1; mk <= 32; mk <<= 1) e2 += __shfl_xor(e2, mk, 64);
        if (lane == 0) e2s[rowgrp * 8 + wid] = e2;
    }
}

// ---------------- combine: merge 2 halves, rescore near-ties -----------------
__global__ __launch_bounds__(256) void combine_kernel(
    const uint2* __restrict__ partials, const float* __restrict__ csq,
    const float* __restrict__ E, const float* __restrict__ Cg,
    float* __restrict__ out, float* __restrict__ sum2) {
    const int n = blockIdx.x * 256 + threadIdx.x;
    const uint2 ka = partials[(size_t)n * 2];
    const uint2 kb = partials[(size_t)n * 2 + 1];
    unsigned x1 = max(ka.x, kb.x);
    unsigned x2 = max(min(ka.x, kb.x), max(ka.y, kb.y));
    const unsigned m1 = x1 & 0xFFFFFE00u;
    float v1 = __builtin_bit_cast(float, (m1 & 0x80000000u) ? (m1 ^ 0x80000000u) : ~m1);
    int i1 = (int)(NK - 1) - (int)(x1 & 511u);
    const unsigned m2 = x2 & 0xFFFFFE00u;
    const float v2 = __builtin_bit_cast(float, (m2 & 0x80000000u) ? (m2 ^ 0x80000000u) : ~m2);
    const int i2 = (int)(NK - 1) - (int)(x2 & 511u);

    if (v1 - v2 <= DELTA) {  // near-tie: exact fp32 rescore of both candidates
        const float* e = E + (size_t)n * ND;
        const float* c1p = Cg + (size_t)i1 * ND;
        const float* c2p = Cg + (size_t)i2 * ND;
        float d1 = 0.f, d2 = 0.f;
        for (int d = 0; d < ND; d += 4) {
            float4 ev = *(const float4*)(e + d);
            float4 cv1 = *(const float4*)(c1p + d);
            float4 cv2 = *(const float4*)(c2p + d);
            d1 += ev.x * cv1.x + ev.y * cv1.y + ev.z * cv1.z + ev.w * cv1.w;
            d2 += ev.x * cv2.x + ev.y * cv2.y + ev.z * cv2.z + ev.w * cv2.w;
        }
        const float s1 = csq[i1] - 2.f * d1;
        const float s2 = csq[i2] - 2.f * d2;
        if (s2 > s1 || (s2 == s1 && i2 < i1)) { v1 = s2; i1 = i2; } else { v1 = s1; }
    }
    out[1 + n] = (float)i1;
    float s = v1;
#pragma unroll
    for (int mk = 1; mk <= 32; mk <<= 1) s += __shfl_xor(s, mk, 64);
    __shared__ float wsm[4];
    const int lane = threadIdx.x & 63, wd = threadIdx.x >> 6;
    if (lane == 0) wsm[wd] = s;
    __syncthreads();
    if (threadIdx.x == 0) sum2[blockIdx.x] = wsm[0] + wsm[1] + wsm[2] + wsm[3];
}

// ---------------- final: loss = lambda^2 * (sum e^2 + sum row maxima) --------
__global__ __launch_bounds__(256) void final_kernel(const float* __restrict__ e2s,
                                                    const float* __restrict__ sum2,
                                                    float* __restrict__ out) {
    float s = 0.f;
    for (int i = threadIdx.x; i < 4096; i += 256) s += e2s[i];
    for (int i = threadIdx.x; i < 512; i += 256) s += sum2[i];
#pragma unroll
    for (int mk = 1; mk <= 32; mk <<= 1) s += __shfl_xor(s, mk, 64);
    __shared__ float wsm[4];
    const int lane = threadIdx.x & 63, wd = threadIdx.x >> 6;
    if (lane == 0) wsm[wd] = s;
    __syncthreads();
    if (threadIdx.x == 0) out[0] = LM2 * (wsm[0] + wsm[1] + wsm[2] + wsm[3]);
}

extern "C" void kernel_launch(void* const* d_in, const int* in_sizes, int n_in,
                              void* d_out, int out_size, void* d_ws, size_t ws_size,
                              hipStream_t stream) {
    (void)n_in; (void)out_size; (void)ws_size;
    const float* E = (const float*)d_in[0];
    const float* Cg = (const float*)d_in[1];
    float* out = (float*)d_out;

    // ws (floats): csq[512] | e2s[4096] | sum2[512] | Cf16 (256KB) | partials (2MB)
    float* wsf = (float*)d_ws;
    float* csq = wsf;
    float* e2s = wsf + 512;
    float* sum2 = wsf + 4608;
    unsigned short* Cf = (unsigned short*)(wsf + 5120);
    uint2* partials = (uint2*)(wsf + 5120 + 65536);

    const int N = in_sizes[0] / ND;  // 131072
    const int nblk = (N >> 8) * 2;   // 512 row-groups x 2 col-halves = 1024

    prep_kernel<<<NK, 64, 0, stream>>>(Cg, csq, Cf);
    kmeans_mfma<<<nblk, 512, 0, stream>>>(E, Cf, csq, partials, e2s);
    combine_kernel<<<N / 256, 256, 0, stream>>>(partials, csq, E, Cg, out, sum2);
    final_kernel<<<1, 256, 0, stream>>>(e2s, sum2, out);
}

// Round 23
// 90.108 us; speedup vs baseline: 2.0040x; 1.2084x over previous
//
#include <hip/hip_runtime.h>

#define ND 256       // embedding dim
#define NK 512       // centroids
#define LM2 0.0625f  // lambda^2
#define DELTA 0.25f  // approx top-2 gap below this -> exact fp32 rescore

typedef _Float16 f16x8 __attribute__((ext_vector_type(8)));
typedef float f32x4 __attribute__((ext_vector_type(4)));
typedef unsigned short u16x8 __attribute__((ext_vector_type(8)));
typedef unsigned short u16x4 __attribute__((ext_vector_type(4)));

// async 16B global->LDS (zero VGPR staging). LDS dest is wave-uniform base
// (HW adds lane*16); global src is per-lane.
#define GLD16(GSRC, LDST)                                                      \
    __builtin_amdgcn_global_load_lds(                                         \
        (const __attribute__((address_space(1))) void*)(GSRC),                \
        (__attribute__((address_space(3))) void*)(LDST), 16, 0, 0)

// ---------------- prep: csq[k] + fp16 centroids in per-64col-panel frag order --
// Cf layout: [panel 8][krow 32][col 64][8], krow = (d>>5)*4 + ((d>>3)&3).
// The 16B granule serves as the MFMA A-operand fragment (16 centroids x 32 k).
__global__ __launch_bounds__(64) void prep_kernel(const float* __restrict__ Cg,
                                                  float* __restrict__ csq,
                                                  unsigned short* __restrict__ Cf) {
    const int k = blockIdx.x, lane = threadIdx.x;
    float4 v = *(const float4*)(Cg + (size_t)k * ND + lane * 4);
    float s = v.x * v.x + v.y * v.y + v.z * v.z + v.w * v.w;
#pragma unroll
    for (int m = 1; m <= 32; m <<= 1) s += __shfl_xor(s, m, 64);
    if (lane == 0) csq[k] = s;
    u16x4 h;
    h[0] = __builtin_bit_cast(unsigned short, (_Float16)v.x);
    h[1] = __builtin_bit_cast(unsigned short, (_Float16)v.y);
    h[2] = __builtin_bit_cast(unsigned short, (_Float16)v.z);
    h[3] = __builtin_bit_cast(unsigned short, (_Float16)v.w);
    const int panel = k >> 6, col = k & 63;
    const int krow = (lane >> 3) * 4 + ((lane >> 1) & 3);  // d0 = lane*4
    const size_t idx = ((size_t)panel << 14) + ((((size_t)krow << 6) + col) << 3) + ((lane & 1) << 2);
    *(u16x4*)(Cf + idx) = h;
}

// ---------------- main: OPERAND-SWAPPED MFMA, 32 rows/wave, 2x B-reuse -------
// grid 512 x 512 thr: 256 rows/block (8 waves x 32), ONE generation (2 bl/CU).
// D[centroid][row] = mfma(A=centroid-frag, B=E-frag). Each centroid ds_read
// feeds TWO MFMAs (E row-groups g=0,1). Per-lane state ~100 regs (no spill:
// r19-measured WRITE_SIZE 2 MB). Session champion: 90.3 us total.
__global__ __launch_bounds__(512, 2) void kmeans_mfma(
    const float* __restrict__ E, const unsigned short* __restrict__ Cf,
    const float* __restrict__ csq, uint2* __restrict__ partials,
    float* __restrict__ e2s) {
    __shared__ unsigned short Bbuf[2][16384];  // 2 x 32 KB

    const int tid = threadIdx.x;
    const int lane = tid & 63, wid = tid >> 6;  // wid 0..7
    const int l15 = lane & 15, l4 = lane >> 4;
    const int rowbase = blockIdx.x << 8;  // 256 rows/block
    const int wrow = rowbase + wid * 32;  // 32 rows/wave

    // ---- issue panel 0 staging (flies during E-load); 4 slots per wave ----
#pragma unroll
    for (int i = 0; i < 4; ++i)
        GLD16(Cf + (((size_t)(wid * 4 + i) * 64 + lane) << 3),
              &Bbuf[0][(size_t)(wid * 4 + i) << 9]);

    // ---- E load: rows wrow+g*16+l15 (g=0,1), chunks of 4 ks ----
    f16x8 Ef[2][8];  // [g][ks], 64 VGPR; B-frag: col=l15(row), k=l4*8
    float e2 = 0.f;
#pragma unroll
    for (int g = 0; g < 2; ++g) {
        const float* ap = E + (size_t)(wrow + g * 16 + l15) * ND + l4 * 8;
#pragma unroll
        for (int half = 0; half < 2; ++half) {
            float4 t[8];
#pragma unroll
            for (int q = 0; q < 4; ++q) {
                t[q * 2]     = *(const float4*)(ap + (half * 4 + q) * 32);
                t[q * 2 + 1] = *(const float4*)(ap + (half * 4 + q) * 32 + 4);
            }
#pragma unroll
            for (int q = 0; q < 4; ++q) {
                float4 v0 = t[q * 2], v1 = t[q * 2 + 1];
                e2 += v0.x * v0.x + v0.y * v0.y + v0.z * v0.z + v0.w * v0.w +
                      v1.x * v1.x + v1.y * v1.y + v1.z * v1.z + v1.w * v1.w;
                u16x8 h;
                h[0] = __builtin_bit_cast(unsigned short, (_Float16)v0.x);
                h[1] = __builtin_bit_cast(unsigned short, (_Float16)v0.y);
                h[2] = __builtin_bit_cast(unsigned short, (_Float16)v0.z);
                h[3] = __builtin_bit_cast(unsigned short, (_Float16)v0.w);
                h[4] = __builtin_bit_cast(unsigned short, (_Float16)v1.x);
                h[5] = __builtin_bit_cast(unsigned short, (_Float16)v1.y);
                h[6] = __builtin_bit_cast(unsigned short, (_Float16)v1.z);
                h[7] = __builtin_bit_cast(unsigned short, (_Float16)v1.w);
                Ef[g][half * 4 + q] = __builtin_bit_cast(f16x8, h);
            }
        }
    }

    unsigned k1[2] = {0u, 0u}, k2[2] = {0u, 0u};  // per row-group top-2 keys

#pragma unroll 1
    for (int p = 0; p < 8; ++p) {
        __syncthreads();  // drains own vmcnt: panel p staged; buf[(p+1)&1] free
        if (p < 7) {      // issue next panel (lands during this panel's compute)
            const unsigned short* gsrc = Cf + ((size_t)(p + 1) << 14);
            unsigned short* ldst = (unsigned short*)Bbuf[(p + 1) & 1];
#pragma unroll
            for (int i = 0; i < 4; ++i)
                GLD16(gsrc + (((size_t)(wid * 4 + i) * 64 + lane) << 3),
                      &ldst[(size_t)(wid * 4 + i) << 9]);
        }
        const unsigned short* cur = Bbuf[p & 1];
        // 4 centroid 16-tiles per panel; each A-frag read feeds BOTH row-groups
#pragma unroll
        for (int n = 0; n < 4; ++n) {
            const float4 csp = *(const float4*)(csq + (p << 6) + n * 16 + l4 * 4);
            f32x4 a0 = {}, a1 = {};
#pragma unroll
            for (int ks = 0; ks < 8; ++ks) {
                const u16x8 bfr =
                    *(const u16x8*)&cur[(size_t)((((ks << 2) + l4) << 6) + n * 16 + l15) << 3];
                const f16x8 cf = __builtin_bit_cast(f16x8, bfr);  // A-frag: 16 centroids x 32k
                a0 = __builtin_amdgcn_mfma_f32_16x16x32_f16(cf, Ef[0][ks], a0, 0, 0, 0);
                a1 = __builtin_amdgcn_mfma_f32_16x16x32_f16(cf, Ef[1][ks], a1, 0, 0, 0);
            }
            // fold: lane holds centroids c = p*64+n*16+l4*4+j for row (l15, g)
            const unsigned kbase = (unsigned)(NK - 1 - ((p << 6) + n * 16 + l4 * 4));
            const float cs[4] = {csp.x, csp.y, csp.z, csp.w};
#pragma unroll
            for (int g = 0; g < 2; ++g) {
                const f32x4 ag = g ? a1 : a0;
#pragma unroll
                for (int j = 0; j < 4; ++j) {
                    const float s = fmaf(-2.f, ag[j], cs[j]);
                    const unsigned b = __builtin_bit_cast(unsigned, s);
                    const unsigned mono = b ^ ((unsigned)((int)b >> 31) | 0x80000000u);
                    const unsigned key = (mono & 0xFFFFFE00u) | (kbase - (unsigned)j);
                    const unsigned mn = min(k1[g], key);
                    k1[g] = max(k1[g], key);
                    k2[g] = max(k2[g], mn);
                }
            }
        }
    }

    // ---- merge across the 4 l4-lane-groups (rows are per-(l15,g)) ----
#pragma unroll
    for (int g = 0; g < 2; ++g) {
        unsigned a = k1[g], b2 = k2[g];
#pragma unroll
        for (int mk = 16; mk <= 32; mk <<= 1) {
            const unsigned oa = __shfl_xor(a, mk, 64);
            const unsigned ob = __shfl_xor(b2, mk, 64);
            const unsigned mn = min(a, oa);
            a = max(a, oa);
            b2 = max(max(b2, ob), mn);
        }
        if (l4 == 0) {
            uint2 o;
            o.x = a;
            o.y = b2;
            partials[wrow + g * 16 + l15] = o;  // FINAL top-2 for this row
        }
    }

    // ---- e2 partial (each element counted exactly once chip-wide) ----
#pragma unroll
    for (int mk = 1; mk <= 32; mk <<= 1) e2 += __shfl_xor(e2, mk, 64);
    if (lane == 0) e2s[blockIdx.x * 8 + wid] = e2;
}

// ---------------- combine: decode final top-2, rescore near-ties -------------
__global__ __launch_bounds__(256) void combine_kernel(
    const uint2* __restrict__ partials, const float* __restrict__ csq,
    const float* __restrict__ E, const float* __restrict__ Cg,
    float* __restrict__ out, float* __restrict__ sum2) {
    const int n = blockIdx.x * 256 + threadIdx.x;
    const uint2 kk = partials[n];
    const unsigned m1 = kk.x & 0xFFFFFE00u;
    float v1 = __builtin_bit_cast(float, (m1 & 0x80000000u) ? (m1 ^ 0x80000000u) : ~m1);
    int i1 = (int)(NK - 1) - (int)(kk.x & 511u);
    const unsigned m2 = kk.y & 0xFFFFFE00u;
    const float v2 = __builtin_bit_cast(float, (m2 & 0x80000000u) ? (m2 ^ 0x80000000u) : ~m2);
    const int i2 = (int)(NK - 1) - (int)(kk.y & 511u);

    if (v1 - v2 <= DELTA) {  // near-tie: exact fp32 rescore of both candidates
        const float* e = E + (size_t)n * ND;
        const float* c1p = Cg + (size_t)i1 * ND;
        const float* c2p = Cg + (size_t)i2 * ND;
        float d1 = 0.f, d2 = 0.f;
        for (int d = 0; d < ND; d += 4) {
            float4 ev = *(const float4*)(e + d);
            float4 cv1 = *(const float4*)(c1p + d);
            float4 cv2 = *(const float4*)(c2p + d);
            d1 += ev.x * cv1.x + ev.y * cv1.y + ev.z * cv1.z + ev.w * cv1.w;
            d2 += ev.x * cv2.x + ev.y * cv2.y + ev.z * cv2.z + ev.w * cv2.w;
        }
        const float s1 = csq[i1] - 2.f * d1;
        const float s2 = csq[i2] - 2.f * d2;
        if (s2 > s1 || (s2 == s1 && i2 < i1)) { v1 = s2; i1 = i2; } else { v1 = s1; }
    }
    out[1 + n] = (float)i1;
    float s = v1;
#pragma unroll
    for (int mk = 1; mk <= 32; mk <<= 1) s += __shfl_xor(s, mk, 64);
    __shared__ float wsm[4];
    const int lane = threadIdx.x & 63, wd = threadIdx.x >> 6;
    if (lane == 0) wsm[wd] = s;
    __syncthreads();
    if (threadIdx.x == 0) sum2[blockIdx.x] = wsm[0] + wsm[1] + wsm[2] + wsm[3];
}

// ---------------- final: loss = lambda^2 * (sum e^2 + sum row maxima) --------
__global__ __launch_bounds__(256) void final_kernel(const float* __restrict__ e2s,
                                                    const float* __restrict__ sum2,
                                                    float* __restrict__ out) {
    float s = 0.f;
    for (int i = threadIdx.x; i < 4096; i += 256) s += e2s[i];
    for (int i = threadIdx.x; i < 512; i += 256) s += sum2[i];
#pragma unroll
    for (int mk = 1; mk <= 32; mk <<= 1) s += __shfl_xor(s, mk, 64);
    __shared__ float wsm[4];
    const int lane = threadIdx.x & 63, wd = threadIdx.x >> 6;
    if (lane == 0) wsm[wd] = s;
    __syncthreads();
    if (threadIdx.x == 0) out[0] = LM2 * (wsm[0] + wsm[1] + wsm[2] + wsm[3]);
}

extern "C" void kernel_launch(void* const* d_in, const int* in_sizes, int n_in,
                              void* d_out, int out_size, void* d_ws, size_t ws_size,
                              hipStream_t stream) {
    (void)n_in; (void)out_size; (void)ws_size;
    const float* E = (const float*)d_in[0];
    const float* Cg = (const float*)d_in[1];
    float* out = (float*)d_out;

    // ws (floats): csq[512] | e2s[4096] | sum2[512] | Cf16 (256KB) | partials (1MB)
    float* wsf = (float*)d_ws;
    float* csq = wsf;
    float* e2s = wsf + 512;
    float* sum2 = wsf + 4608;
    unsigned short* Cf = (unsigned short*)(wsf + 5120);
    uint2* partials = (uint2*)(wsf + 5120 + 65536);

    const int N = in_sizes[0] / ND;  // 131072
    const int nblk = N >> 8;         // 512 blocks of 256 rows (one generation)

    prep_kernel<<<NK, 64, 0, stream>>>(Cg, csq, Cf);
    kmeans_mfma<<<nblk, 512, 0, stream>>>(E, Cf, csq, partials, e2s);
    combine_kernel<<<N / 256, 256, 0, stream>>>(partials, csq, E, Cg, out, sum2);
    final_kernel<<<1, 256, 0, stream>>>(e2s, sum2, out);
}